// Round 1
// baseline (66.410 us; speedup 1.0000x reference)
//
#include <hip/hip_runtime.h>
#include <hip/hip_bf16.h>

typedef __bf16 bf16x8 __attribute__((ext_vector_type(8)));
typedef float  f32x4  __attribute__((ext_vector_type(4)));

// Fused SO(2)-equivariant linear layer:
//   h = relu(s @ W1 + b1); w = h @ W2 + b2; out[e,o] = complex_contract(x[e], w[e,o,:])
// One wave = 64 edges. GEMMs via mfma_f32_16x16x32_bf16, fp32 accumulate.
__global__ __launch_bounds__(256) void so2_fused_kernel(
    const float* __restrict__ x, const float* __restrict__ s,
    const float* __restrict__ W1, const float* __restrict__ b1v,
    const float* __restrict__ W2, const float* __restrict__ b2v,
    float* __restrict__ out, int E)
{
  // W1^T [j=64][k=64] bf16, XOR-swizzled rows (128 B row stride)
  __shared__ unsigned short lds_w1t[64 * 64];
  // W2^T [d=32][k=64] bf16, XOR-swizzled
  __shared__ unsigned short lds_w2t[32 * 64];
  __shared__ float lds_b1[64];
  __shared__ float lds_b2[32];
  // per-wave scratch: first h as bf16 [edge=64][hid=64], then w as f32 [d=32][edge=64]
  __shared__ char lds_hw[4][8192];

  const int tid  = threadIdx.x;
  const int wid  = tid >> 6;
  const int lane = tid & 63;
  const int lrow = lane & 15;   // MFMA row/col within 16
  const int lg   = lane >> 4;   // lane quadrant -> k-group

  const int web = blockIdx.x * 256 + wid * 64;  // wave edge base
  const bool wave_active = (web < E);

  // ---- issue s loads early, directly in A-fragment shape ----
  // A frag (16x16x32): lane holds row = lrow, k = kq*32 + lg*8 + i (8 consecutive)
  f32x4 sv[4][4];  // [mtile][k-chunk: {k0 lo, k0 hi, k1 lo, k1 hi}]
  {
    const int base_e = wave_active ? web : 0;
    #pragma unroll
    for (int mt = 0; mt < 4; ++mt) {
      int er = base_e + mt * 16 + lrow;
      er = er < E ? er : E - 1;
      const float* sp = s + (size_t)er * 64 + lg * 8;
      sv[mt][0] = *(const f32x4*)(sp);
      sv[mt][1] = *(const f32x4*)(sp + 4);
      sv[mt][2] = *(const f32x4*)(sp + 32);
      sv[mt][3] = *(const f32x4*)(sp + 36);
    }
  }

  // ---- stage weights to LDS as bf16, transposed, XOR-swizzled ----
  // lds_w1t[j][k] = bf16(W1[k][j]); byte = j*128 + k*2, ^ ((j&7)<<4)
  #pragma unroll
  for (int it = 0; it < 16; ++it) {
    int i = it * 256 + tid;              // i = k*64 + j, coalesced read
    int k = i >> 6, j = i & 63;
    int byte = (j << 7) + (k << 1);
    byte ^= (j & 7) << 4;
    *(unsigned short*)((char*)lds_w1t + byte) =
        __builtin_bit_cast(unsigned short, (__bf16)W1[i]);
  }
  #pragma unroll
  for (int it = 0; it < 8; ++it) {
    int i = it * 256 + tid;              // i = k*32 + d
    int k = i >> 5, d = i & 31;
    int byte = (d << 7) + (k << 1);
    byte ^= (d & 7) << 4;
    *(unsigned short*)((char*)lds_w2t + byte) =
        __builtin_bit_cast(unsigned short, (__bf16)W2[i]);
  }
  if (tid < 64) lds_b1[tid] = b1v[tid];
  if (tid >= 64 && tid < 96) lds_b2[tid - 64] = b2v[tid - 64];
  __syncthreads();
  if (!wave_active) return;

  char* hbuf = lds_hw[wid];

  // ---- convert s to bf16 A-fragments ----
  bf16x8 af[4][2];
  #pragma unroll
  for (int mt = 0; mt < 4; ++mt) {
    #pragma unroll
    for (int h = 0; h < 2; ++h) {
      #pragma unroll
      for (int i = 0; i < 4; ++i) {
        af[mt][h][i]     = (__bf16)sv[mt][h * 2][i];
        af[mt][h][i + 4] = (__bf16)sv[mt][h * 2 + 1][i];
      }
    }
  }

  // ---- GEMM1: h = relu(s @ W1 + b1); write bf16 h[edge][hid] to LDS ----
  #pragma unroll
  for (int nt = 0; nt < 4; ++nt) {
    const int j = nt * 16 + lrow;        // hid column (B frag col = lrow)
    bf16x8 bfr[2];
    #pragma unroll
    for (int h = 0; h < 2; ++h) {
      int byte = (j << 7) + ((h * 32 + lg * 8) << 1);
      byte ^= (j & 7) << 4;
      bfr[h] = *(const bf16x8*)((const char*)lds_w1t + byte);
    }
    const float bj = lds_b1[j];
    #pragma unroll
    for (int mt = 0; mt < 4; ++mt) {
      f32x4 acc = {0.f, 0.f, 0.f, 0.f};
      acc = __builtin_amdgcn_mfma_f32_16x16x32_bf16(af[mt][0], bfr[0], acc, 0, 0, 0);
      acc = __builtin_amdgcn_mfma_f32_16x16x32_bf16(af[mt][1], bfr[1], acc, 0, 0, 0);
      // D layout: col = lrow (=j), row = lg*4 + r  (within this 16x16 tile)
      #pragma unroll
      for (int r = 0; r < 4; ++r) {
        float hv = fmaxf(acc[r] + bj, 0.f);
        int row = mt * 16 + lg * 4 + r;  // edge within wave
        int byte = (row << 7) + (j << 1);
        byte ^= (row & 7) << 4;
        *(unsigned short*)(hbuf + byte) =
            __builtin_bit_cast(unsigned short, (__bf16)hv);
      }
    }
  }

  // ---- GEMM2: w = h @ W2 + b2 ----
  bf16x8 a2[4][2];
  #pragma unroll
  for (int mt = 0; mt < 4; ++mt) {
    #pragma unroll
    for (int h = 0; h < 2; ++h) {
      int row = mt * 16 + lrow;
      int byte = (row << 7) + ((h * 32 + lg * 8) << 1);
      byte ^= (row & 7) << 4;
      a2[mt][h] = *(const bf16x8*)(hbuf + byte);
    }
  }
  bf16x8 b2f[2][2];
  #pragma unroll
  for (int nt = 0; nt < 2; ++nt) {
    #pragma unroll
    for (int h = 0; h < 2; ++h) {
      int d = nt * 16 + lrow;
      int byte = (d << 7) + ((h * 32 + lg * 8) << 1);
      byte ^= (d & 7) << 4;
      b2f[nt][h] = *(const bf16x8*)((const char*)lds_w2t + byte);
    }
  }
  f32x4 wacc[4][2];
  #pragma unroll
  for (int mt = 0; mt < 4; ++mt) {
    #pragma unroll
    for (int nt = 0; nt < 2; ++nt) {
      f32x4 acc = {0.f, 0.f, 0.f, 0.f};
      acc = __builtin_amdgcn_mfma_f32_16x16x32_bf16(a2[mt][0], b2f[nt][0], acc, 0, 0, 0);
      acc = __builtin_amdgcn_mfma_f32_16x16x32_bf16(a2[mt][1], b2f[nt][1], acc, 0, 0, 0);
      wacc[mt][nt] = acc;
    }
  }

  // ---- write w (fp32) transposed [d=32][edge=64] into hbuf (reuse), b128 writes ----
  #pragma unroll
  for (int nt = 0; nt < 2; ++nt) {
    const int d = nt * 16 + lrow;
    const float bd = lds_b2[d];
    #pragma unroll
    for (int mt = 0; mt < 4; ++mt) {
      f32x4 wout;
      #pragma unroll
      for (int r = 0; r < 4; ++r) wout[r] = wacc[mt][nt][r] + bd;
      int byte = (d << 8) + ((mt * 16 + lg * 4) << 2);  // row stride 256 B
      byte ^= (d & 7) << 4;
      *(f32x4*)(hbuf + byte) = wout;
    }
  }

  // ---- epilogue: one edge per lane, complex contraction in fp32 ----
  const int e = web + lane;
  const float* xp = x + (size_t)(e < E ? e : E - 1) * 8;
  f32x4 x0 = *(const f32x4*)xp;        // {xr0, xi0, xr1, xi1}
  f32x4 x1 = *(const f32x4*)(xp + 4);  // {xr2, xi2, xr3, xi3}

  float wv32[32];
  #pragma unroll
  for (int d = 0; d < 32; ++d) {
    int byte = (d << 8) + (lane << 2);
    byte ^= (d & 7) << 4;              // d uniform per instr -> conflict-free
    wv32[d] = *(const float*)(hbuf + byte);
  }

  f32x4 o0, o1;
  #pragma unroll
  for (int o = 0; o < 4; ++o) {
    float orv = 0.f, oiv = 0.f;
    #pragma unroll
    for (int p = 0; p < 4; ++p) {
      float xr = (p < 2) ? x0[2 * p]     : x1[2 * p - 4];
      float xi = (p < 2) ? x0[2 * p + 1] : x1[2 * p - 3];
      float wr = wv32[o * 8 + 2 * p];
      float wi = wv32[o * 8 + 2 * p + 1];
      orv = fmaf(xr, wr, orv);
      orv = fmaf(-xi, wi, orv);
      oiv = fmaf(xr, wi, oiv);
      oiv = fmaf(xi, wr, oiv);
    }
    if (o < 2) { o0[2 * o] = orv; o0[2 * o + 1] = oiv; }
    else       { o1[2 * o - 4] = orv; o1[2 * o - 3] = oiv; }
  }
  if (e < E) {
    float* op = out + (size_t)e * 8;
    *(f32x4*)op       = o0;
    *(f32x4*)(op + 4) = o1;
  }
}

extern "C" void kernel_launch(void* const* d_in, const int* in_sizes, int n_in,
                              void* d_out, int out_size, void* d_ws, size_t ws_size,
                              hipStream_t stream) {
  const float* x  = (const float*)d_in[0];
  const float* s  = (const float*)d_in[1];
  const float* W1 = (const float*)d_in[2];
  const float* b1 = (const float*)d_in[3];
  const float* W2 = (const float*)d_in[4];
  const float* b2 = (const float*)d_in[5];
  float* out = (float*)d_out;
  const int E = in_sizes[0] / 8;               // x is (E, 4, 2)
  const int blocks = (E + 255) / 256;          // 256 edges per block (4 waves)
  so2_fused_kernel<<<blocks, 256, 0, stream>>>(x, s, W1, b1, W2, b2, out, E);
}